// Round 1
// baseline (194.339 us; speedup 1.0000x reference)
//
#include <hip/hip_runtime.h>
#include <hip/hip_bf16.h>

// MultiHeadAttention fused pipeline, MI355X gfx950.
// B=8, S=1024 (N=1023 + 1 global), HID=512, H=8, D=64.
// Stages: gemm_proj<0> q,k -> bf16 [B][H][S][D]; gemm_proj<1> v -> bf16 [B][H][D][S] (transposed);
//         attn_fused -> ctx bf16 [B][S][512]; gemm_proj<2> -> f32 out.
// No-max softmax: scores bounded, exp2 with log2e folded into Q scale and bias table.

typedef __attribute__((ext_vector_type(8)))  __bf16 bf16x8;
typedef __attribute__((ext_vector_type(16))) float  f32x16;

__device__ inline f32x16 zero16(){
  f32x16 z;
  #pragma unroll
  for (int i=0;i<16;i++) z[i] = 0.0f;
  return z;
}

__device__ inline unsigned short f2bf(float x){           // RNE f32->bf16
  unsigned u = __float_as_uint(x);
  u += 0x7fffu + ((u>>16)&1u);
  return (unsigned short)(u>>16);
}
__device__ inline unsigned f2bf_pair(float a, float b){   // pack 2 bf16 into dword
  unsigned ua = __float_as_uint(a); ua += 0x7fffu + ((ua>>16)&1u);
  unsigned ub = __float_as_uint(b); ub += 0x7fffu + ((ub>>16)&1u);
  return (ua>>16) | (ub & 0xffff0000u);
}

// D[r][c] = sum_k RA[r][k]*RB[c][k]  (K=512), 128x128 tile, 4 waves, wave-tile 64x64.
// MODE 0: RA=X f32 (M=8192), bias[c], out bf16 [B][H][S][D], *outscale
// MODE 1: RA=W f32 (M=512), RB=X, bias[r], out bf16 [B][H][D][S]
// MODE 2: RA=ctx bf16 (M=8192), bias[c], out f32 flat [8192][512]
template<int MODE>
__global__ __launch_bounds__(256)
void gemm_proj(const void* RA_, const float* RB, const float* bias,
               void* OUT, float outscale)
{
  __shared__ unsigned short lda[128*40];   // 40-pad: 4-way max LDS conflicts, 16B-aligned rows
  __shared__ unsigned short ldb[128*40];
  const int tid  = threadIdx.x;
  const int r0   = blockIdx.x*128, c0 = blockIdx.y*128;
  const int w    = tid>>6, lane = tid&63, lo = lane&31, hi = lane>>5;
  const int wr   = (w>>1)*64, wc = (w&1)*64;
  const int arow = tid>>1, kb = (tid&1)*16;

  f32x16 acc[2][2];
  #pragma unroll
  for (int i=0;i<2;i++)
    #pragma unroll
    for (int j=0;j<2;j++) acc[i][j] = zero16();

  float4 ra[4], rb4[4];
  uint4  ra16[2];

  // prefetch k-step 0
  if (MODE==2){
    const uint4* p = (const uint4*)((const unsigned short*)RA_ + (r0+arow)*512 + kb);
    ra16[0]=p[0]; ra16[1]=p[1];
  } else {
    const float4* p = (const float4*)((const float*)RA_ + (r0+arow)*512 + kb);
    ra[0]=p[0]; ra[1]=p[1]; ra[2]=p[2]; ra[3]=p[3];
  }
  {
    const float4* p = (const float4*)(RB + (c0+arow)*512 + kb);
    rb4[0]=p[0]; rb4[1]=p[1]; rb4[2]=p[2]; rb4[3]=p[3];
  }

  for (int ks=0; ks<16; ++ks){
    __syncthreads();
    {
      uint4 w0, w1;
      if (MODE==2){ w0 = ra16[0]; w1 = ra16[1]; }
      else {
        w0.x = f2bf_pair(ra[0].x, ra[0].y); w0.y = f2bf_pair(ra[0].z, ra[0].w);
        w0.z = f2bf_pair(ra[1].x, ra[1].y); w0.w = f2bf_pair(ra[1].z, ra[1].w);
        w1.x = f2bf_pair(ra[2].x, ra[2].y); w1.y = f2bf_pair(ra[2].z, ra[2].w);
        w1.z = f2bf_pair(ra[3].x, ra[3].y); w1.w = f2bf_pair(ra[3].z, ra[3].w);
      }
      uint4* pa = (uint4*)&lda[arow*40 + kb];
      pa[0] = w0; pa[1] = w1;
      uint4 v0, v1;
      v0.x = f2bf_pair(rb4[0].x, rb4[0].y); v0.y = f2bf_pair(rb4[0].z, rb4[0].w);
      v0.z = f2bf_pair(rb4[1].x, rb4[1].y); v0.w = f2bf_pair(rb4[1].z, rb4[1].w);
      v1.x = f2bf_pair(rb4[2].x, rb4[2].y); v1.y = f2bf_pair(rb4[2].z, rb4[2].w);
      v1.z = f2bf_pair(rb4[3].x, rb4[3].y); v1.w = f2bf_pair(rb4[3].z, rb4[3].w);
      uint4* pb = (uint4*)&ldb[arow*40 + kb];
      pb[0] = v0; pb[1] = v1;
    }
    __syncthreads();
    if (ks < 15){
      const int k0 = (ks+1)*32;
      if (MODE==2){
        const uint4* p = (const uint4*)((const unsigned short*)RA_ + (r0+arow)*512 + k0 + kb);
        ra16[0]=p[0]; ra16[1]=p[1];
      } else {
        const float4* p = (const float4*)((const float*)RA_ + (r0+arow)*512 + k0 + kb);
        ra[0]=p[0]; ra[1]=p[1]; ra[2]=p[2]; ra[3]=p[3];
      }
      const float4* p = (const float4*)(RB + (c0+arow)*512 + k0 + kb);
      rb4[0]=p[0]; rb4[1]=p[1]; rb4[2]=p[2]; rb4[3]=p[3];
    }
    #pragma unroll
    for (int kf=0; kf<2; ++kf){
      bf16x8 af0 = *(const bf16x8*)&lda[(wr+lo)*40    + kf*16 + hi*8];
      bf16x8 af1 = *(const bf16x8*)&lda[(wr+32+lo)*40 + kf*16 + hi*8];
      bf16x8 bg0 = *(const bf16x8*)&ldb[(wc+lo)*40    + kf*16 + hi*8];
      bf16x8 bg1 = *(const bf16x8*)&ldb[(wc+32+lo)*40 + kf*16 + hi*8];
      acc[0][0] = __builtin_amdgcn_mfma_f32_32x32x16_bf16(af0, bg0, acc[0][0], 0,0,0);
      acc[0][1] = __builtin_amdgcn_mfma_f32_32x32x16_bf16(af0, bg1, acc[0][1], 0,0,0);
      acc[1][0] = __builtin_amdgcn_mfma_f32_32x32x16_bf16(af1, bg0, acc[1][0], 0,0,0);
      acc[1][1] = __builtin_amdgcn_mfma_f32_32x32x16_bf16(af1, bg1, acc[1][1], 0,0,0);
    }
  }

  // epilogue; C/D layout (verified m74/m101): col = lane&31, row = (r&3)+8*(r>>2)+4*(lane>>5)
  #pragma unroll
  for (int mi=0;mi<2;mi++){
    #pragma unroll
    for (int ni=0;ni<2;ni++){
      #pragma unroll
      for (int r=0;r<16;r++){
        const int rl = wr + mi*32 + (r&3) + 8*(r>>2) + 4*hi;
        const int cl = wc + ni*32 + lo;
        const int rg = r0 + rl, cg = c0 + cl;
        float v = acc[mi][ni][r];
        if (MODE==0){
          v = (v + bias[cg]) * outscale;
          const int bb = rg>>10, s = rg&1023, h = cg>>6, d = cg&63;
          ((unsigned short*)OUT)[(((bb*8+h)*1024)+s)*64 + d] = f2bf(v);
        } else if (MODE==1){
          v = v + bias[rg];
          const int h = rg>>6, d = rg&63, bb = cg>>10, s = cg&1023;
          ((unsigned short*)OUT)[(((bb*8+h)*64)+d)*1024 + s] = f2bf(v);
        } else {
          ((float*)OUT)[rg*512 + cg] = v + bias[cg];
        }
      }
    }
  }
}

// Fused attention. Block = 512 threads = 8 waves; wave w = head w; 32 q-rows per block.
// No-max softmax: p = exp2(score' + bias') with log2e pre-folded.
__global__ __launch_bounds__(512)
void attn_fused(const unsigned short* qh, const unsigned short* kh,
                const unsigned short* vhT, const int* ab,
                const float* bias_table, const float* vbias,
                unsigned short* ctx)
{
  __shared__ float tbl[8*260];      // per-head: [0..254]=table*log2e, 255=-inf, 256=vbias*log2e
  __shared__ int   abt[32*33];      // bias-index tile, TRANSPOSED [t_local][q_local], padded
  __shared__ float pbuf[8][32*33];  // per-wave P bounce, [q_local][t_local] f32, padded

  const int tid = threadIdx.x;
  const int b   = blockIdx.y;
  const int s0  = blockIdx.x*32;

  for (int i = tid; i < 8*257; i += 512){
    const int h = i/257, idx = i - h*257;
    float v;
    if (idx < 255)      v = bias_table[idx*8 + h];
    else if (idx == 255) v = -1.0e30f;      // ab==255 -> -inf mask
    else                 v = vbias[h];      // global row/col
    tbl[h*260 + idx] = v * 1.4426950408889634f;
  }

  const int w = tid>>6, lane = tid&63, lo = lane&31, hi = lane>>5;
  const unsigned short* qbase = qh  + (size_t)(b*8+w)*1024*64;
  const unsigned short* kbase = kh  + (size_t)(b*8+w)*1024*64;
  const unsigned short* vbase = vhT + (size_t)(b*8+w)*64*1024;

  // Q fragments (A operand, rows = s0+lo, k=d), held across the whole t loop
  bf16x8 qf[4];
  #pragma unroll
  for (int kf=0; kf<4; ++kf)
    qf[kf] = *(const bf16x8*)&qbase[(s0+lo)*64 + kf*16 + hi*8];

  f32x16 accv[2]; accv[0] = zero16(); accv[1] = zero16();
  float lsum[16];
  #pragma unroll
  for (int r=0;r<16;r++) lsum[r] = 0.0f;

  const int e0   = tid*2;
  const int str  = e0>>5;      // staging q-row
  const int stc  = e0&31;      // staging t-col (even)
  const int srow = s0 + str;

  for (int t0=0; t0<1024; t0+=32){
    __syncthreads();           // prev abt fully consumed (also covers tbl on first iter)
    #pragma unroll
    for (int j=0;j<2;j++){
      const int tc = t0 + stc + j;
      int v = 256;             // sentinel: global row/col -> vbias
      if (srow < 1023 && tc < 1023) v = ab[((size_t)b*1023 + srow)*1023 + tc];
      abt[(stc+j)*33 + str] = v;
    }
    __syncthreads();

    // scores tile [32q x 32t] = Q * K^T
    f32x16 sc = zero16();
    #pragma unroll
    for (int kf=0; kf<4; ++kf){
      bf16x8 kfr = *(const bf16x8*)&kbase[(t0+lo)*64 + kf*16 + hi*8];
      sc = __builtin_amdgcn_mfma_f32_32x32x16_bf16(qf[kf], kfr, sc, 0,0,0);
    }

    // bias lookup + exp2; truncate p to bf16 (consistently for lsum and P)
    #pragma unroll
    for (int r=0;r<16;r++){
      const int rq  = (r&3) + 8*(r>>2) + 4*hi;   // q row of this acc reg
      const int idx = abt[lo*33 + rq];           // read transposed: row=t(lo), col=q
      const float bv = tbl[w*260 + idx];
      float p = exp2f(sc[r] + bv);
      p = __uint_as_float(__float_as_uint(p) & 0xffff0000u);
      lsum[r] += p;
      pbuf[w][rq*33 + lo] = p;                   // [q][t], conflict-free (33 pad)
    }
    asm volatile("s_waitcnt lgkmcnt(0)" ::: "memory");  // P bounce RAW within wave

    // read P as A fragments (row=lo, k=t consecutive), pack truncated bf16 pairs
    unsigned pf[2][4];
    #pragma unroll
    for (int kf=0; kf<2; ++kf){
      #pragma unroll
      for (int pr=0; pr<4; ++pr){
        const float a = pbuf[w][lo*33 + kf*16 + hi*8 + 2*pr];
        const float c = pbuf[w][lo*33 + kf*16 + hi*8 + 2*pr + 1];
        pf[kf][pr] = (__float_as_uint(a)>>16) | (__float_as_uint(c) & 0xffff0000u);
      }
    }
    // PV: ctx[32q x 64d] += P * V  (V from transposed [B][H][D][S] -> contiguous B frags)
    #pragma unroll
    for (int dc=0; dc<2; ++dc){
      #pragma unroll
      for (int kf=0; kf<2; ++kf){
        bf16x8 vf = *(const bf16x8*)&vbase[(dc*32+lo)*1024 + t0 + kf*16 + hi*8];
        union { unsigned u[4]; bf16x8 v; } pc;
        pc.u[0]=pf[kf][0]; pc.u[1]=pf[kf][1]; pc.u[2]=pf[kf][2]; pc.u[3]=pf[kf][3];
        accv[dc] = __builtin_amdgcn_mfma_f32_32x32x16_bf16(pc.v, vf, accv[dc], 0,0,0);
      }
    }
  }

  // row sums: reduce over the 32 lanes (t-cols) sharing each row, then reciprocal
  #pragma unroll
  for (int r=0;r<16;r++){
    #pragma unroll
    for (int m=1;m<32;m<<=1) lsum[r] += __shfl_xor(lsum[r], m, 64);
    lsum[r] = 1.0f / lsum[r];
  }
  // store ctx bf16 [B][S][H*64+d], coalesced along d=lo
  #pragma unroll
  for (int dc=0; dc<2; ++dc){
    #pragma unroll
    for (int r=0;r<16;r++){
      const int rq = (r&3) + 8*(r>>2) + 4*hi;
      const float v = accv[dc][r] * lsum[r];
      ctx[((size_t)b*1024 + s0 + rq)*512 + w*64 + dc*32 + lo] = f2bf(v);
    }
  }
}

extern "C" void kernel_launch(void* const* d_in, const int* in_sizes, int n_in,
                              void* d_out, int out_size, void* d_ws, size_t ws_size,
                              hipStream_t stream)
{
  const float* q    = (const float*)d_in[0];
  const float* k    = (const float*)d_in[1];
  const float* v    = (const float*)d_in[2];
  const int*   ab   = (const int*)  d_in[3];
  const float* Wq   = (const float*)d_in[4];
  const float* bq   = (const float*)d_in[5];
  const float* Wk   = (const float*)d_in[6];
  const float* bk   = (const float*)d_in[7];
  const float* Wv   = (const float*)d_in[8];
  const float* bv   = (const float*)d_in[9];
  const float* Wo   = (const float*)d_in[10];
  const float* bo   = (const float*)d_in[11];
  const float* btab = (const float*)d_in[12];
  const float* vbia = (const float*)d_in[13];

  char* ws = (char*)d_ws;
  unsigned short* qh  = (unsigned short*)(ws);
  unsigned short* kh  = (unsigned short*)(ws + ((size_t)8<<20));
  unsigned short* vhT = (unsigned short*)(ws + ((size_t)16<<20));
  unsigned short* ctx = (unsigned short*)(ws + ((size_t)24<<20));

  const float SCALE_Q = 0.125f * 1.4426950408889634f;  // D^-0.5 * log2(e)

  gemm_proj<0><<<dim3(64,4), 256, 0, stream>>>(q,  Wq, bq, qh,  SCALE_Q);
  gemm_proj<0><<<dim3(64,4), 256, 0, stream>>>(k,  Wk, bk, kh,  1.0f);
  gemm_proj<1><<<dim3(4,64), 256, 0, stream>>>(Wv, v,  bv, vhT, 1.0f);
  attn_fused <<<dim3(32,8), 512, 0, stream>>>(qh, kh, vhT, ab, btab, vbia, ctx);
  gemm_proj<2><<<dim3(64,4), 256, 0, stream>>>(ctx, Wo, bo, d_out, 1.0f);
}

// Round 3
// 150.528 us; speedup vs baseline: 1.2910x; 1.2910x over previous
//
#include <hip/hip_runtime.h>
#include <hip/hip_bf16.h>

// MultiHeadAttention fused pipeline, MI355X gfx950.
// B=8, S=1024 (N=1023 + 1 global), HID=512, H=8, D=64.
// Stages: gemm_proj<0> q,k -> bf16 [B][H][S][D]; gemm_proj<1> v -> bf16 [B][H][D][S] (transposed);
//         attn_fused -> ctx bf16 [B][S][512]; gemm_proj<2> -> f32 out.
// No-max softmax: scores bounded, exp2 with log2e folded into Q scale and bias table.
// R1: latency-hiding restructure — register prefetch (ab/K/V one iter ahead),
//     double-buffered abt (1 barrier/iter), raw s_barrier (no vmcnt drain).
// R2: identical resubmit (R1 bench was lost to an infra failure).

typedef __attribute__((ext_vector_type(8)))  __bf16 bf16x8;
typedef __attribute__((ext_vector_type(16))) float  f32x16;

__device__ inline f32x16 zero16(){
  f32x16 z;
  #pragma unroll
  for (int i=0;i<16;i++) z[i] = 0.0f;
  return z;
}

__device__ inline unsigned short f2bf(float x){           // RNE f32->bf16
  unsigned u = __float_as_uint(x);
  u += 0x7fffu + ((u>>16)&1u);
  return (unsigned short)(u>>16);
}
__device__ inline unsigned f2bf_pair(float a, float b){   // pack 2 bf16 into dword
  unsigned ua = __float_as_uint(a); ua += 0x7fffu + ((ua>>16)&1u);
  unsigned ub = __float_as_uint(b); ub += 0x7fffu + ((ub>>16)&1u);
  return (ua>>16) | (ub & 0xffff0000u);
}

__device__ inline void bar_lgkm(){   // LDS-visibility barrier WITHOUT vmcnt drain
  asm volatile("s_waitcnt lgkmcnt(0)" ::: "memory");
  __builtin_amdgcn_s_barrier();
}

// D[r][c] = sum_k RA[r][k]*RB[c][k]  (K=512), 128x128 tile, 4 waves, wave-tile 64x64.
// MODE 0: RA=X f32 (M=8192), bias[c], out bf16 [B][H][S][D], *outscale
// MODE 1: RA=W f32 (M=512), RB=X, bias[r], out bf16 [B][H][D][S]
// MODE 2: RA=ctx bf16 (M=8192), bias[c], out f32 flat [8192][512]
template<int MODE>
__global__ __launch_bounds__(256)
void gemm_proj(const void* RA_, const float* RB, const float* bias,
               void* OUT, float outscale)
{
  __shared__ unsigned short lda[128*40];   // 40-pad: 4-way max LDS conflicts, 16B-aligned rows
  __shared__ unsigned short ldb[128*40];
  const int tid  = threadIdx.x;
  const int r0   = blockIdx.x*128, c0 = blockIdx.y*128;
  const int w    = tid>>6, lane = tid&63, lo = lane&31, hi = lane>>5;
  const int wr   = (w>>1)*64, wc = (w&1)*64;
  const int arow = tid>>1, kb = (tid&1)*16;

  f32x16 acc[2][2];
  #pragma unroll
  for (int i=0;i<2;i++)
    #pragma unroll
    for (int j=0;j<2;j++) acc[i][j] = zero16();

  float4 ra[4], rb4[4];
  uint4  ra16[2];

  // prefetch k-step 0
  if (MODE==2){
    const uint4* p = (const uint4*)((const unsigned short*)RA_ + (r0+arow)*512 + kb);
    ra16[0]=p[0]; ra16[1]=p[1];
  } else {
    const float4* p = (const float4*)((const float*)RA_ + (r0+arow)*512 + kb);
    ra[0]=p[0]; ra[1]=p[1]; ra[2]=p[2]; ra[3]=p[3];
  }
  {
    const float4* p = (const float4*)(RB + (c0+arow)*512 + kb);
    rb4[0]=p[0]; rb4[1]=p[1]; rb4[2]=p[2]; rb4[3]=p[3];
  }

  for (int ks=0; ks<16; ++ks){
    // barrier 1: all waves done consuming prev LDS tiles (reads fed MFMAs already)
    bar_lgkm();
    {
      uint4 w0, w1;
      if (MODE==2){ w0 = ra16[0]; w1 = ra16[1]; }
      else {
        w0.x = f2bf_pair(ra[0].x, ra[0].y); w0.y = f2bf_pair(ra[0].z, ra[0].w);
        w0.z = f2bf_pair(ra[1].x, ra[1].y); w0.w = f2bf_pair(ra[1].z, ra[1].w);
        w1.x = f2bf_pair(ra[2].x, ra[2].y); w1.y = f2bf_pair(ra[2].z, ra[2].w);
        w1.z = f2bf_pair(ra[3].x, ra[3].y); w1.w = f2bf_pair(ra[3].z, ra[3].w);
      }
      uint4* pa = (uint4*)&lda[arow*40 + kb];
      pa[0] = w0; pa[1] = w1;
      uint4 v0, v1;
      v0.x = f2bf_pair(rb4[0].x, rb4[0].y); v0.y = f2bf_pair(rb4[0].z, rb4[0].w);
      v0.z = f2bf_pair(rb4[1].x, rb4[1].y); v0.w = f2bf_pair(rb4[1].z, rb4[1].w);
      v1.x = f2bf_pair(rb4[2].x, rb4[2].y); v1.y = f2bf_pair(rb4[2].z, rb4[2].w);
      v1.z = f2bf_pair(rb4[3].x, rb4[3].y); v1.w = f2bf_pair(rb4[3].z, rb4[3].w);
      uint4* pb = (uint4*)&ldb[arow*40 + kb];
      pb[0] = v0; pb[1] = v1;
    }
    // issue next k-step's loads NOW; they stay in flight across the barrier
    // (raw s_barrier does not drain vmcnt) and complete during the MFMA section.
    if (ks < 15){
      const int k0 = (ks+1)*32;
      if (MODE==2){
        const uint4* p = (const uint4*)((const unsigned short*)RA_ + (r0+arow)*512 + k0 + kb);
        ra16[0]=p[0]; ra16[1]=p[1];
      } else {
        const float4* p = (const float4*)((const float*)RA_ + (r0+arow)*512 + k0 + kb);
        ra[0]=p[0]; ra[1]=p[1]; ra[2]=p[2]; ra[3]=p[3];
      }
      const float4* p = (const float4*)(RB + (c0+arow)*512 + k0 + kb);
      rb4[0]=p[0]; rb4[1]=p[1]; rb4[2]=p[2]; rb4[3]=p[3];
    }
    // barrier 2: LDS writes visible
    bar_lgkm();
    #pragma unroll
    for (int kf=0; kf<2; ++kf){
      bf16x8 af0 = *(const bf16x8*)&lda[(wr+lo)*40    + kf*16 + hi*8];
      bf16x8 af1 = *(const bf16x8*)&lda[(wr+32+lo)*40 + kf*16 + hi*8];
      bf16x8 bg0 = *(const bf16x8*)&ldb[(wc+lo)*40    + kf*16 + hi*8];
      bf16x8 bg1 = *(const bf16x8*)&ldb[(wc+32+lo)*40 + kf*16 + hi*8];
      acc[0][0] = __builtin_amdgcn_mfma_f32_32x32x16_bf16(af0, bg0, acc[0][0], 0,0,0);
      acc[0][1] = __builtin_amdgcn_mfma_f32_32x32x16_bf16(af0, bg1, acc[0][1], 0,0,0);
      acc[1][0] = __builtin_amdgcn_mfma_f32_32x32x16_bf16(af1, bg0, acc[1][0], 0,0,0);
      acc[1][1] = __builtin_amdgcn_mfma_f32_32x32x16_bf16(af1, bg1, acc[1][1], 0,0,0);
    }
  }

  // epilogue; C/D layout (verified m74/m101): col = lane&31, row = (r&3)+8*(r>>2)+4*(lane>>5)
  #pragma unroll
  for (int mi=0;mi<2;mi++){
    #pragma unroll
    for (int ni=0;ni<2;ni++){
      #pragma unroll
      for (int r=0;r<16;r++){
        const int rl = wr + mi*32 + (r&3) + 8*(r>>2) + 4*hi;
        const int cl = wc + ni*32 + lo;
        const int rg = r0 + rl, cg = c0 + cl;
        float v = acc[mi][ni][r];
        if (MODE==0){
          v = (v + bias[cg]) * outscale;
          const int bb = rg>>10, s = rg&1023, h = cg>>6, d = cg&63;
          ((unsigned short*)OUT)[(((bb*8+h)*1024)+s)*64 + d] = f2bf(v);
        } else if (MODE==1){
          v = v + bias[rg];
          const int h = rg>>6, d = rg&63, bb = cg>>10, s = cg&1023;
          ((unsigned short*)OUT)[(((bb*8+h)*64)+d)*1024 + s] = f2bf(v);
        } else {
          ((float*)OUT)[rg*512 + cg] = v + bias[cg];
        }
      }
    }
  }
}

// Fused attention. Block = 512 threads = 8 waves; wave w = head w; 32 q-rows per block.
// No-max softmax: p = exp2(score' + bias') with log2e pre-folded.
// ab / K / V register-prefetched one t-tile ahead; abt double-buffered; 1 barrier/iter.
__global__ __launch_bounds__(512)
void attn_fused(const unsigned short* qh, const unsigned short* kh,
                const unsigned short* vhT, const int* ab,
                const float* bias_table, const float* vbias,
                unsigned short* ctx)
{
  __shared__ float tbl[8*260];        // per-head: [0..254]=table*log2e, 255=-inf, 256=vbias*log2e
  __shared__ int   abt[2][32*33];     // bias-index tile, double-buffered, TRANSPOSED [t][q], padded
  __shared__ float pbuf[8][32*33];    // per-wave P bounce, [q][t] f32, padded

  const int tid = threadIdx.x;
  const int b   = blockIdx.y;
  const int s0  = blockIdx.x*32;

  for (int i = tid; i < 8*257; i += 512){
    const int h = i/257, idx = i - h*257;
    float v;
    if (idx < 255)       v = bias_table[idx*8 + h];
    else if (idx == 255) v = -1.0e30f;      // ab==255 -> -inf mask
    else                 v = vbias[h];      // global row/col
    tbl[h*260 + idx] = v * 1.4426950408889634f;
  }

  const int w = tid>>6, lane = tid&63, lo = lane&31, hi = lane>>5;
  const unsigned short* qbase = qh  + (size_t)(b*8+w)*1024*64;
  const unsigned short* kbase = kh  + (size_t)(b*8+w)*1024*64;
  const unsigned short* vbase = vhT + (size_t)(b*8+w)*64*1024;

  // Q fragments (A operand, rows = s0+lo, k=d), held across the whole t loop
  bf16x8 qf[4];
  #pragma unroll
  for (int kf=0; kf<4; ++kf)
    qf[kf] = *(const bf16x8*)&qbase[(s0+lo)*64 + kf*16 + hi*8];

  f32x16 accv[2]; accv[0] = zero16(); accv[1] = zero16();
  float lsum[16];
  #pragma unroll
  for (int r=0;r<16;r++) lsum[r] = 0.0f;

  const int e0   = tid*2;
  const int str  = e0>>5;      // staging q-row
  const int stc  = e0&31;      // staging t-col (even)
  const int srow = s0 + str;
  const size_t abrow = (size_t)(b*1023 + srow)*1023;

  // ---- prefetch tile 0 ----
  int av0 = 256, av1 = 256;
  if (srow < 1023){
    if (stc     < 1023) av0 = ab[abrow + stc];
    if (stc + 1 < 1023) av1 = ab[abrow + stc + 1];
  }
  bf16x8 kc[4], kn[4], vc[4], vn[4];
  #pragma unroll
  for (int i=0;i<4;i++) kc[i] = *(const bf16x8*)&kbase[lo*64 + i*16 + hi*8];
  #pragma unroll
  for (int dc=0;dc<2;dc++)
    #pragma unroll
    for (int j=0;j<2;j++)
      vc[dc*2+j] = *(const bf16x8*)&vbase[(dc*32+lo)*1024 + j*16 + hi*8];

  for (int t0=0; t0<1024; t0+=32){
    const int cur = (t0>>5)&1;
    const int tn  = (t0+32)&1023;              // wrapped prefetch target (last iter: dummy, unused)
    // stage abt[cur] from prefetched regs (vmcnt wait happens here, 1 iter of slack)
    abt[cur][(stc  )*33 + str] = av0;
    abt[cur][(stc+1)*33 + str] = av1;
    // issue next ab loads
    int na0 = 256, na1 = 256;
    if (t0 < 992 && srow < 1023){
      const int tc = t0 + 32 + stc;
      if (tc     < 1023) na0 = ab[abrow + tc];
      if (tc + 1 < 1023) na1 = ab[abrow + tc + 1];
    }

    // scores tile [32q x 32t] = Q * K^T (K prefetched last iter)
    f32x16 sc = zero16();
    sc = __builtin_amdgcn_mfma_f32_32x32x16_bf16(qf[0], kc[0], sc, 0,0,0);
    sc = __builtin_amdgcn_mfma_f32_32x32x16_bf16(qf[1], kc[1], sc, 0,0,0);
    sc = __builtin_amdgcn_mfma_f32_32x32x16_bf16(qf[2], kc[2], sc, 0,0,0);
    sc = __builtin_amdgcn_mfma_f32_32x32x16_bf16(qf[3], kc[3], sc, 0,0,0);
    // issue next K loads (in flight across the barrier)
    #pragma unroll
    for (int i=0;i<4;i++) kn[i] = *(const bf16x8*)&kbase[(tn+lo)*64 + i*16 + hi*8];

    // abt[cur] visible to all waves; vmcnt NOT drained (raw barrier)
    bar_lgkm();

    // bias lookup + exp2; truncate p to bf16 (consistently for lsum and P)
    #pragma unroll
    for (int r=0;r<16;r++){
      const int rq  = (r&3) + 8*(r>>2) + 4*hi;   // q row of this acc reg
      const int idx = abt[cur][lo*33 + rq];      // read transposed: row=t(lo), col=q
      const float bv = tbl[w*260 + idx];
      float p = __builtin_amdgcn_exp2f(sc[r] + bv);
      p = __uint_as_float(__float_as_uint(p) & 0xffff0000u);
      lsum[r] += p;
      pbuf[w][rq*33 + lo] = p;                   // [q][t], conflict-free (33 pad)
    }
    asm volatile("s_waitcnt lgkmcnt(0)" ::: "memory");  // P bounce RAW within wave

    // read P as A fragments (row=lo, k=t consecutive), pack truncated bf16 pairs
    unsigned pf[2][4];
    #pragma unroll
    for (int kf=0; kf<2; ++kf){
      #pragma unroll
      for (int pr=0; pr<4; ++pr){
        const float a = pbuf[w][lo*33 + kf*16 + hi*8 + 2*pr];
        const float c = pbuf[w][lo*33 + kf*16 + hi*8 + 2*pr + 1];
        pf[kf][pr] = (__float_as_uint(a)>>16) | (__float_as_uint(c) & 0xffff0000u);
      }
    }
    // issue next V loads before PV so they overlap the MFMAs + next iter front
    #pragma unroll
    for (int dc=0;dc<2;dc++)
      #pragma unroll
      for (int j=0;j<2;j++)
        vn[dc*2+j] = *(const bf16x8*)&vbase[(dc*32+lo)*1024 + tn + j*16 + hi*8];

    // PV: ctx[32q x 64d] += P * V  (V from transposed [B][H][D][S] -> contiguous B frags)
    #pragma unroll
    for (int dc=0; dc<2; ++dc){
      #pragma unroll
      for (int kf=0; kf<2; ++kf){
        union { unsigned u[4]; bf16x8 v; } pc;
        pc.u[0]=pf[kf][0]; pc.u[1]=pf[kf][1]; pc.u[2]=pf[kf][2]; pc.u[3]=pf[kf][3];
        accv[dc] = __builtin_amdgcn_mfma_f32_32x32x16_bf16(pc.v, vc[dc*2+kf], accv[dc], 0,0,0);
      }
    }
    // rotate prefetch buffers
    av0 = na0; av1 = na1;
    #pragma unroll
    for (int i=0;i<4;i++){ kc[i] = kn[i]; vc[i] = vn[i]; }
  }

  // row sums: reduce over the 32 lanes (t-cols) sharing each row, then reciprocal
  #pragma unroll
  for (int r=0;r<16;r++){
    #pragma unroll
    for (int m=1;m<32;m<<=1) lsum[r] += __shfl_xor(lsum[r], m, 64);
    lsum[r] = 1.0f / lsum[r];
  }
  // store ctx bf16 [B][S][H*64+d], coalesced along d=lo
  #pragma unroll
  for (int dc=0; dc<2; ++dc){
    #pragma unroll
    for (int r=0;r<16;r++){
      const int rq = (r&3) + 8*(r>>2) + 4*hi;
      const float v = accv[dc][r] * lsum[r];
      ctx[((size_t)b*1024 + s0 + rq)*512 + w*64 + dc*32 + lo] = f2bf(v);
    }
  }
}

extern "C" void kernel_launch(void* const* d_in, const int* in_sizes, int n_in,
                              void* d_out, int out_size, void* d_ws, size_t ws_size,
                              hipStream_t stream)
{
  const float* q    = (const float*)d_in[0];
  const float* k    = (const float*)d_in[1];
  const float* v    = (const float*)d_in[2];
  const int*   ab   = (const int*)  d_in[3];
  const float* Wq   = (const float*)d_in[4];
  const float* bq   = (const float*)d_in[5];
  const float* Wk   = (const float*)d_in[6];
  const float* bk   = (const float*)d_in[7];
  const float* Wv   = (const float*)d_in[8];
  const float* bv   = (const float*)d_in[9];
  const float* Wo   = (const float*)d_in[10];
  const float* bo   = (const float*)d_in[11];
  const float* btab = (const float*)d_in[12];
  const float* vbia = (const float*)d_in[13];

  char* ws = (char*)d_ws;
  unsigned short* qh  = (unsigned short*)(ws);
  unsigned short* kh  = (unsigned short*)(ws + ((size_t)8<<20));
  unsigned short* vhT = (unsigned short*)(ws + ((size_t)16<<20));
  unsigned short* ctx = (unsigned short*)(ws + ((size_t)24<<20));

  const float SCALE_Q = 0.125f * 1.4426950408889634f;  // D^-0.5 * log2(e)

  gemm_proj<0><<<dim3(64,4), 256, 0, stream>>>(q,  Wq, bq, qh,  SCALE_Q);
  gemm_proj<0><<<dim3(64,4), 256, 0, stream>>>(k,  Wk, bk, kh,  1.0f);
  gemm_proj<1><<<dim3(4,64), 256, 0, stream>>>(Wv, v,  bv, vhT, 1.0f);
  attn_fused <<<dim3(32,8), 512, 0, stream>>>(qh, kh, vhT, ab, btab, vbia, ctx);
  gemm_proj<2><<<dim3(64,4), 256, 0, stream>>>(ctx, Wo, bo, d_out, 1.0f);
}

// Round 4
// 148.773 us; speedup vs baseline: 1.3063x; 1.0118x over previous
//
#include <hip/hip_runtime.h>
#include <hip/hip_bf16.h>

// MultiHeadAttention fused pipeline, MI355X gfx950.
// B=8, S=1024 (N=1023 + 1 global), HID=512, H=8, D=64.
// Stages: qkv_proj (merged, 768 blocks) -> qh/kh [B][H][S][D], vhT [B][H][D][S];
//         attn_fused -> ctx bf16 [B][S][512]; gemm_proj<2> -> f32 out.
// No-max softmax: scores bounded, exp2 with log2e folded into Q scale and bias table.
// R3: attn barrier ELIMINATED — ab bias indices loaded per-wave via coalesced
//     register prefetch (no abt LDS tile, no cross-wave dependency, waves free-run).
//     Q/K/V projections merged into one 768-block dispatch (3 blocks/CU overlap).

typedef __attribute__((ext_vector_type(8)))  __bf16 bf16x8;
typedef __attribute__((ext_vector_type(16))) float  f32x16;

__device__ inline f32x16 zero16(){
  f32x16 z;
  #pragma unroll
  for (int i=0;i<16;i++) z[i] = 0.0f;
  return z;
}

__device__ inline unsigned short f2bf(float x){           // RNE f32->bf16
  unsigned u = __float_as_uint(x);
  u += 0x7fffu + ((u>>16)&1u);
  return (unsigned short)(u>>16);
}
__device__ inline unsigned f2bf_pair(float a, float b){   // pack 2 bf16 into dword
  unsigned ua = __float_as_uint(a); ua += 0x7fffu + ((ua>>16)&1u);
  unsigned ub = __float_as_uint(b); ub += 0x7fffu + ((ub>>16)&1u);
  return (ua>>16) | (ub & 0xffff0000u);
}

__device__ inline void bar_lgkm(){   // LDS-visibility barrier WITHOUT vmcnt drain
  asm volatile("s_waitcnt lgkmcnt(0)" ::: "memory");
  __builtin_amdgcn_s_barrier();
}

// ---------------------------------------------------------------------------
// Merged Q/K/V projection. 768 blocks (256 each), 256 threads, 128x128 tile.
// sel=0: qh = (q Wq^T + bq)*scaleq   [B][H][S][D]
// sel=1: kh = (k Wk^T + bk)          [B][H][S][D]
// sel=2: vhT = (v Wv^T + bv)^T       [B][H][D][S]  (computed as Wv * v^T)
// ---------------------------------------------------------------------------
__global__ __launch_bounds__(256)
void qkv_proj(const float* xq, const float* xk, const float* xv,
              const float* Wq, const float* Wk, const float* Wv,
              const float* bq, const float* bk, const float* bv,
              unsigned short* qh, unsigned short* kh, unsigned short* vhT,
              float scaleq)
{
  __shared__ unsigned short lda[128*40];   // 40-pad rows
  __shared__ unsigned short ldb[128*40];
  const int bid = blockIdx.x;
  const int sel = bid >> 8;                // uniform per block
  const int t   = bid & 255;
  const float *RA, *RB, *bias;
  int r0, c0;
  if (sel == 0){ RA = xq; RB = Wq; bias = bq; r0 = (t&63)*128; c0 = (t>>6)*128; }
  else if (sel == 1){ RA = xk; RB = Wk; bias = bk; r0 = (t&63)*128; c0 = (t>>6)*128; }
  else { RA = Wv; RB = xv; bias = bv; r0 = (t&3)*128; c0 = (t>>2)*128; }

  const int tid  = threadIdx.x;
  const int w    = tid>>6, lane = tid&63, lo = lane&31, hi = lane>>5;
  const int wr   = (w>>1)*64, wc = (w&1)*64;
  const int arow = tid>>1, kb = (tid&1)*16;

  f32x16 acc[2][2];
  #pragma unroll
  for (int i=0;i<2;i++)
    #pragma unroll
    for (int j=0;j<2;j++) acc[i][j] = zero16();

  float4 ra[4], rb4[4];
  {
    const float4* p = (const float4*)(RA + (r0+arow)*512 + kb);
    ra[0]=p[0]; ra[1]=p[1]; ra[2]=p[2]; ra[3]=p[3];
    const float4* pq = (const float4*)(RB + (c0+arow)*512 + kb);
    rb4[0]=pq[0]; rb4[1]=pq[1]; rb4[2]=pq[2]; rb4[3]=pq[3];
  }

  for (int ks=0; ks<16; ++ks){
    bar_lgkm();    // prev LDS tiles consumed
    {
      uint4 w0, w1;
      w0.x = f2bf_pair(ra[0].x, ra[0].y); w0.y = f2bf_pair(ra[0].z, ra[0].w);
      w0.z = f2bf_pair(ra[1].x, ra[1].y); w0.w = f2bf_pair(ra[1].z, ra[1].w);
      w1.x = f2bf_pair(ra[2].x, ra[2].y); w1.y = f2bf_pair(ra[2].z, ra[2].w);
      w1.z = f2bf_pair(ra[3].x, ra[3].y); w1.w = f2bf_pair(ra[3].z, ra[3].w);
      uint4* pa = (uint4*)&lda[arow*40 + kb];
      pa[0] = w0; pa[1] = w1;
      uint4 v0, v1;
      v0.x = f2bf_pair(rb4[0].x, rb4[0].y); v0.y = f2bf_pair(rb4[0].z, rb4[0].w);
      v0.z = f2bf_pair(rb4[1].x, rb4[1].y); v0.w = f2bf_pair(rb4[1].z, rb4[1].w);
      v1.x = f2bf_pair(rb4[2].x, rb4[2].y); v1.y = f2bf_pair(rb4[2].z, rb4[2].w);
      v1.z = f2bf_pair(rb4[3].x, rb4[3].y); v1.w = f2bf_pair(rb4[3].z, rb4[3].w);
      uint4* pb = (uint4*)&ldb[arow*40 + kb];
      pb[0] = v0; pb[1] = v1;
    }
    if (ks < 15){
      const int k0 = (ks+1)*32;
      const float4* p = (const float4*)(RA + (r0+arow)*512 + k0 + kb);
      ra[0]=p[0]; ra[1]=p[1]; ra[2]=p[2]; ra[3]=p[3];
      const float4* pq = (const float4*)(RB + (c0+arow)*512 + k0 + kb);
      rb4[0]=pq[0]; rb4[1]=pq[1]; rb4[2]=pq[2]; rb4[3]=pq[3];
    }
    bar_lgkm();    // LDS writes visible; prefetch stays in flight (no vmcnt drain)
    #pragma unroll
    for (int kf=0; kf<2; ++kf){
      bf16x8 af0 = *(const bf16x8*)&lda[(wr+lo)*40    + kf*16 + hi*8];
      bf16x8 af1 = *(const bf16x8*)&lda[(wr+32+lo)*40 + kf*16 + hi*8];
      bf16x8 bg0 = *(const bf16x8*)&ldb[(wc+lo)*40    + kf*16 + hi*8];
      bf16x8 bg1 = *(const bf16x8*)&ldb[(wc+32+lo)*40 + kf*16 + hi*8];
      acc[0][0] = __builtin_amdgcn_mfma_f32_32x32x16_bf16(af0, bg0, acc[0][0], 0,0,0);
      acc[0][1] = __builtin_amdgcn_mfma_f32_32x32x16_bf16(af0, bg1, acc[0][1], 0,0,0);
      acc[1][0] = __builtin_amdgcn_mfma_f32_32x32x16_bf16(af1, bg0, acc[1][0], 0,0,0);
      acc[1][1] = __builtin_amdgcn_mfma_f32_32x32x16_bf16(af1, bg1, acc[1][1], 0,0,0);
    }
  }

  // epilogue; C/D layout: col = lane&31, row = (r&3)+8*(r>>2)+4*(lane>>5)
  #pragma unroll
  for (int mi=0;mi<2;mi++){
    #pragma unroll
    for (int ni=0;ni<2;ni++){
      #pragma unroll
      for (int r=0;r<16;r++){
        const int rl = wr + mi*32 + (r&3) + 8*(r>>2) + 4*hi;
        const int cl = wc + ni*32 + lo;
        const int rg = r0 + rl, cg = c0 + cl;
        float v = acc[mi][ni][r];
        if (sel == 0){
          v = (v + bias[cg]) * scaleq;
          const int bb = rg>>10, s = rg&1023, h = cg>>6, d = cg&63;
          qh[(((bb*8+h)*1024)+s)*64 + d] = f2bf(v);
        } else if (sel == 1){
          v = v + bias[cg];
          const int bb = rg>>10, s = rg&1023, h = cg>>6, d = cg&63;
          kh[(((bb*8+h)*1024)+s)*64 + d] = f2bf(v);
        } else {
          v = v + bias[rg];
          const int h = rg>>6, d = rg&63, bb = cg>>10, s = cg&1023;
          vhT[(((bb*8+h)*64)+d)*1024 + s] = f2bf(v);
        }
      }
    }
  }
}

// ---------------------------------------------------------------------------
// Out projection: out[8192][512] = ctx(bf16) Wo^T + bo, f32 out.
// ---------------------------------------------------------------------------
template<int MODE>
__global__ __launch_bounds__(256)
void gemm_proj(const void* RA_, const float* RB, const float* bias,
               void* OUT, float outscale)
{
  __shared__ unsigned short lda[128*40];
  __shared__ unsigned short ldb[128*40];
  const int tid  = threadIdx.x;
  const int r0   = blockIdx.x*128, c0 = blockIdx.y*128;
  const int w    = tid>>6, lane = tid&63, lo = lane&31, hi = lane>>5;
  const int wr   = (w>>1)*64, wc = (w&1)*64;
  const int arow = tid>>1, kb = (tid&1)*16;

  f32x16 acc[2][2];
  #pragma unroll
  for (int i=0;i<2;i++)
    #pragma unroll
    for (int j=0;j<2;j++) acc[i][j] = zero16();

  float4 rb4[4];
  uint4  ra16[2];

  {
    const uint4* p = (const uint4*)((const unsigned short*)RA_ + (r0+arow)*512 + kb);
    ra16[0]=p[0]; ra16[1]=p[1];
    const float4* pq = (const float4*)(RB + (c0+arow)*512 + kb);
    rb4[0]=pq[0]; rb4[1]=pq[1]; rb4[2]=pq[2]; rb4[3]=pq[3];
  }

  for (int ks=0; ks<16; ++ks){
    bar_lgkm();
    {
      uint4* pa = (uint4*)&lda[arow*40 + kb];
      pa[0] = ra16[0]; pa[1] = ra16[1];
      uint4 v0, v1;
      v0.x = f2bf_pair(rb4[0].x, rb4[0].y); v0.y = f2bf_pair(rb4[0].z, rb4[0].w);
      v0.z = f2bf_pair(rb4[1].x, rb4[1].y); v0.w = f2bf_pair(rb4[1].z, rb4[1].w);
      v1.x = f2bf_pair(rb4[2].x, rb4[2].y); v1.y = f2bf_pair(rb4[2].z, rb4[2].w);
      v1.z = f2bf_pair(rb4[3].x, rb4[3].y); v1.w = f2bf_pair(rb4[3].z, rb4[3].w);
      uint4* pb = (uint4*)&ldb[arow*40 + kb];
      pb[0] = v0; pb[1] = v1;
    }
    if (ks < 15){
      const int k0 = (ks+1)*32;
      const uint4* p = (const uint4*)((const unsigned short*)RA_ + (r0+arow)*512 + k0 + kb);
      ra16[0]=p[0]; ra16[1]=p[1];
      const float4* pq = (const float4*)(RB + (c0+arow)*512 + k0 + kb);
      rb4[0]=pq[0]; rb4[1]=pq[1]; rb4[2]=pq[2]; rb4[3]=pq[3];
    }
    bar_lgkm();
    #pragma unroll
    for (int kf=0; kf<2; ++kf){
      bf16x8 af0 = *(const bf16x8*)&lda[(wr+lo)*40    + kf*16 + hi*8];
      bf16x8 af1 = *(const bf16x8*)&lda[(wr+32+lo)*40 + kf*16 + hi*8];
      bf16x8 bg0 = *(const bf16x8*)&ldb[(wc+lo)*40    + kf*16 + hi*8];
      bf16x8 bg1 = *(const bf16x8*)&ldb[(wc+32+lo)*40 + kf*16 + hi*8];
      acc[0][0] = __builtin_amdgcn_mfma_f32_32x32x16_bf16(af0, bg0, acc[0][0], 0,0,0);
      acc[0][1] = __builtin_amdgcn_mfma_f32_32x32x16_bf16(af0, bg1, acc[0][1], 0,0,0);
      acc[1][0] = __builtin_amdgcn_mfma_f32_32x32x16_bf16(af1, bg0, acc[1][0], 0,0,0);
      acc[1][1] = __builtin_amdgcn_mfma_f32_32x32x16_bf16(af1, bg1, acc[1][1], 0,0,0);
    }
  }

  #pragma unroll
  for (int mi=0;mi<2;mi++){
    #pragma unroll
    for (int ni=0;ni<2;ni++){
      #pragma unroll
      for (int r=0;r<16;r++){
        const int rl = wr + mi*32 + (r&3) + 8*(r>>2) + 4*hi;
        const int cl = wc + ni*32 + lo;
        const int rg = r0 + rl, cg = c0 + cl;
        ((float*)OUT)[rg*512 + cg] = acc[mi][ni][r] + bias[cg];
      }
    }
  }
}

// ---------------------------------------------------------------------------
// Fused attention, BARRIER-FREE main loop. 512 threads = 8 waves; wave = head.
// ab bias indices: per-wave coalesced register prefetch (lane needs (q=rq,t=lo);
// per acc-reg r the 32 lanes read consecutive t -> one 128B segment).
// K/V/ab all prefetched one t-tile ahead; waves run fully independently.
// ---------------------------------------------------------------------------
__global__ __launch_bounds__(512, 2)
void attn_fused(const unsigned short* qh, const unsigned short* kh,
                const unsigned short* vhT, const int* ab,
                const float* bias_table, const float* vbias,
                unsigned short* ctx)
{
  __shared__ float tbl[8*260];      // per-head: [0..254]=table*log2e, 255=-inf, 256=vbias*log2e
  __shared__ float pbuf[8][32*33];  // per-wave P bounce, [q][t] f32, padded

  const int tid = threadIdx.x;
  const int b   = blockIdx.y;
  const int s0  = blockIdx.x*32;

  for (int i = tid; i < 8*257; i += 512){
    const int h = i/257, idx = i - h*257;
    float v;
    if (idx < 255)       v = bias_table[idx*8 + h];
    else if (idx == 255) v = -1.0e30f;      // ab==255 -> -inf mask
    else                 v = vbias[h];      // global row/col
    tbl[h*260 + idx] = v * 1.4426950408889634f;
  }
  __syncthreads();   // tbl ready; ONLY barrier in the kernel

  const int w = tid>>6, lane = tid&63, lo = lane&31, hi = lane>>5;
  const unsigned short* qbase = qh  + (size_t)(b*8+w)*1024*64;
  const unsigned short* kbase = kh  + (size_t)(b*8+w)*1024*64;
  const unsigned short* vbase = vhT + (size_t)(b*8+w)*64*1024;

  // Q fragments (A operand, rows = s0+lo, k=d), held across the whole t loop
  bf16x8 qf[4];
  #pragma unroll
  for (int kf=0; kf<4; ++kf)
    qf[kf] = *(const bf16x8*)&qbase[(s0+lo)*64 + kf*16 + hi*8];

  f32x16 accv[2]; accv[0] = zero16(); accv[1] = zero16();
  float lsum[16];
  #pragma unroll
  for (int r=0;r<16;r++) lsum[r] = 0.0f;

  // ---- prefetch tile 0: ab indices (16 coalesced dwords/lane), K, V ----
  int av[16], nav[16];
  #pragma unroll
  for (int r=0;r<16;r++){
    const int qr = s0 + 4*hi + (r&3) + 8*(r>>2);
    const int tc = lo;
    av[r] = (qr < 1023 && tc < 1023) ? ab[(size_t)(b*1023 + qr)*1023 + tc] : 256;
  }
  bf16x8 kc[4], kn[4], vc[4], vn[4];
  #pragma unroll
  for (int i=0;i<4;i++) kc[i] = *(const bf16x8*)&kbase[lo*64 + i*16 + hi*8];
  #pragma unroll
  for (int dc=0;dc<2;dc++)
    #pragma unroll
    for (int j=0;j<2;j++)
      vc[dc*2+j] = *(const bf16x8*)&vbase[(dc*32+lo)*1024 + j*16 + hi*8];

  for (int t0=0; t0<1024; t0+=32){
    const int tn = (t0+32)&1023;            // wrapped K/V prefetch target (last iter unused)

    // scores tile [32q x 32t] = Q * K^T (K prefetched last iter)
    f32x16 sc = zero16();
    sc = __builtin_amdgcn_mfma_f32_32x32x16_bf16(qf[0], kc[0], sc, 0,0,0);
    sc = __builtin_amdgcn_mfma_f32_32x32x16_bf16(qf[1], kc[1], sc, 0,0,0);
    sc = __builtin_amdgcn_mfma_f32_32x32x16_bf16(qf[2], kc[2], sc, 0,0,0);
    sc = __builtin_amdgcn_mfma_f32_32x32x16_bf16(qf[3], kc[3], sc, 0,0,0);
    // issue next K loads (hidden under exp/PV of this iter)
    #pragma unroll
    for (int i=0;i<4;i++) kn[i] = *(const bf16x8*)&kbase[(tn+lo)*64 + i*16 + hi*8];

    // bias lookup (idx in registers) + exp2; truncate p to bf16 consistently
    #pragma unroll
    for (int r=0;r<16;r++){
      const int rq  = (r&3) + 8*(r>>2) + 4*hi;   // q row of this acc reg
      const float bv = tbl[w*260 + av[r]];
      float p = __builtin_amdgcn_exp2f(sc[r] + bv);
      p = __uint_as_float(__float_as_uint(p) & 0xffff0000u);
      lsum[r] += p;
      pbuf[w][rq*33 + lo] = p;                   // [q][t], conflict-free (33 pad)
    }
    // issue next ab-index loads (guarded; out-of-range -> sentinel 256)
    {
      const int tt = t0 + 32;
      #pragma unroll
      for (int r=0;r<16;r++){
        const int qr = s0 + 4*hi + (r&3) + 8*(r>>2);
        const int tc = tt + lo;
        nav[r] = (qr < 1023 && tc < 1023) ? ab[(size_t)(b*1023 + qr)*1023 + tc] : 256;
      }
    }
    asm volatile("s_waitcnt lgkmcnt(0)" ::: "memory");  // P bounce RAW within wave

    // read P as A fragments (row=lo, k=t consecutive), pack truncated bf16 pairs
    unsigned pf[2][4];
    #pragma unroll
    for (int kf=0; kf<2; ++kf){
      #pragma unroll
      for (int pr=0; pr<4; ++pr){
        const float a = pbuf[w][lo*33 + kf*16 + hi*8 + 2*pr];
        const float c = pbuf[w][lo*33 + kf*16 + hi*8 + 2*pr + 1];
        pf[kf][pr] = (__float_as_uint(a)>>16) | (__float_as_uint(c) & 0xffff0000u);
      }
    }
    // issue next V loads
    #pragma unroll
    for (int dc=0;dc<2;dc++)
      #pragma unroll
      for (int j=0;j<2;j++)
        vn[dc*2+j] = *(const bf16x8*)&vbase[(dc*32+lo)*1024 + tn + j*16 + hi*8];

    // PV: ctx[32q x 64d] += P * V
    #pragma unroll
    for (int dc=0; dc<2; ++dc){
      #pragma unroll
      for (int kf=0; kf<2; ++kf){
        union { unsigned u[4]; bf16x8 v; } pc;
        pc.u[0]=pf[kf][0]; pc.u[1]=pf[kf][1]; pc.u[2]=pf[kf][2]; pc.u[3]=pf[kf][3];
        accv[dc] = __builtin_amdgcn_mfma_f32_32x32x16_bf16(pc.v, vc[dc*2+kf], accv[dc], 0,0,0);
      }
    }
    // rotate prefetch buffers
    #pragma unroll
    for (int r=0;r<16;r++) av[r] = nav[r];
    #pragma unroll
    for (int i=0;i<4;i++){ kc[i] = kn[i]; vc[i] = vn[i]; }
  }

  // row sums: reduce over the 32 lanes (t-cols) sharing each row, then reciprocal
  #pragma unroll
  for (int r=0;r<16;r++){
    #pragma unroll
    for (int m=1;m<32;m<<=1) lsum[r] += __shfl_xor(lsum[r], m, 64);
    lsum[r] = 1.0f / lsum[r];
  }
  // store ctx bf16 [B][S][H*64+d], coalesced along d=lo
  #pragma unroll
  for (int dc=0; dc<2; ++dc){
    #pragma unroll
    for (int r=0;r<16;r++){
      const int rq = (r&3) + 8*(r>>2) + 4*hi;
      const float v = accv[dc][r] * lsum[r];
      ctx[((size_t)b*1024 + s0 + rq)*512 + w*64 + dc*32 + lo] = f2bf(v);
    }
  }
}

extern "C" void kernel_launch(void* const* d_in, const int* in_sizes, int n_in,
                              void* d_out, int out_size, void* d_ws, size_t ws_size,
                              hipStream_t stream)
{
  const float* q    = (const float*)d_in[0];
  const float* k    = (const float*)d_in[1];
  const float* v    = (const float*)d_in[2];
  const int*   ab   = (const int*)  d_in[3];
  const float* Wq   = (const float*)d_in[4];
  const float* bq   = (const float*)d_in[5];
  const float* Wk   = (const float*)d_in[6];
  const float* bk   = (const float*)d_in[7];
  const float* Wv   = (const float*)d_in[8];
  const float* bv   = (const float*)d_in[9];
  const float* Wo   = (const float*)d_in[10];
  const float* bo   = (const float*)d_in[11];
  const float* btab = (const float*)d_in[12];
  const float* vbia = (const float*)d_in[13];

  char* ws = (char*)d_ws;
  unsigned short* qh  = (unsigned short*)(ws);
  unsigned short* kh  = (unsigned short*)(ws + ((size_t)8<<20));
  unsigned short* vhT = (unsigned short*)(ws + ((size_t)16<<20));
  unsigned short* ctx = (unsigned short*)(ws + ((size_t)24<<20));

  const float SCALE_Q = 0.125f * 1.4426950408889634f;  // D^-0.5 * log2(e)

  qkv_proj<<<768, 256, 0, stream>>>(q, k, v, Wq, Wk, Wv, bq, bk, bv,
                                    qh, kh, vhT, SCALE_Q);
  attn_fused<<<dim3(32,8), 512, 0, stream>>>(qh, kh, vhT, ab, btab, vbia, ctx);
  gemm_proj<2><<<dim3(64,4), 256, 0, stream>>>(ctx, Wo, bo, d_out, 1.0f);
}